// Round 9
// baseline (39.793 us; speedup 1.0000x reference)
//
#include <hip/hip_runtime.h>

#define NPROTO 20
#define SEQ_LEN 512
#define TPB 256               // 4 waves per block; 2 l-positions per thread

// Correctly-rounded a/d via Markstein refinement, given rc = RN(1/d), nd = -d:
// q0 = RN(a*rc); r = fma(nd,q0,a) (exact); q1 = RN(q0 + r*rc) == RN(a/d).
// Bit-exact vs IEEE divide for this kernel's operand families (verified
// absmax=0 in R3/R4/R6/R7/R8 over the full input set):
//  - d = 3.0f constant
//  - d = integer in [1,510], a = exact integer product < 2^18
__device__ __forceinline__ float div_exact(float a, float nd, float rc)
{
    const float q0 = a * rc;
    const float r  = fmaf(nd, q0, a);
    return fmaf(r, rc, q0);
}

// EXPERIMENT R9: byte-identical R7 kernel, launched TWICE per kernel_launch.
// Distinguishes (A) per-replay launch-overhead floor (~21us; dur stays ~22)
// from (B/C) fixed per-dispatch cost (dur doubles to ~44). The second launch
// rewrites identical values -> deterministic, harness-safe.
__global__ __launch_bounds__(TPB)
void adaptive_mask_kernel(const float* __restrict__ tok,
                          const float* __restrict__ sigma,
                          const float* __restrict__ pi,
                          float* __restrict__ out)
{
    const int b = blockIdx.x;
    const int t = threadIdx.x;

    __shared__ float  s_pi[NPROTO];
    __shared__ float4 s_c4[NPROTO + 1];   // compacted {m,aL,aR,rc}; +1 sentinel
    __shared__ int    s_nkept;

    float m = 0.f, aL = 0.f, aR = 0.f, rc = 0.f, piv = 0.f;
    if (t < NPROTO) {
        const int idx = b * NPROTO + t;
        const float tk = tok[idx];
        const float sg = sigma[idx];
        m  = rintf(fminf(fmaxf(tk, 1.0f), 511.0f));   // round-half-even
        aL = (0.001f * sg) * m;                       // CVL*sigma*m
        aR = (0.001f * sg) * (512.0f - m);            // CVR*sigma*(512-m)
        const float den = (m == 511.0f) ? 1.0f : (511.0f - m);
        rc  = 1.0f / den;                             // IEEE RN(1/den)
        piv = pi[idx];
        s_pi[t] = piv;
    }
    __syncthreads();

    if (t < 64) {   // wave 0 only; cross-lane inputs barrier-protected
        float s = 0.0f;
        #pragma unroll
        for (int p = 0; p < NPROTO; ++p) s += s_pi[p];   // sequential, like XLA
        const float mean = s / 20.0f;                    // identical in every lane
        const bool keep = (t < NPROTO) && (piv >= mean);
        const unsigned long long bal = __ballot(keep);
        if (keep) {
            const int dst = (int)__popcll(bal & ((1ull << t) - 1ull));
            s_c4[dst] = make_float4(m, aL, aR, rc);      // own registers -> LDS
        }
        if (t == 0) s_nkept = (int)__popcll(bal);
    }
    __syncthreads();

    const int nkept = __builtin_amdgcn_readfirstlane(s_nkept);
    const float C3 = 1.0f / 3.0f;      // RN(1/3)

    const float lf0 = (float)(2 * t);
    const float lf1 = lf0 + 1.0f;      // exact
    float acc0 = 0.f, acc1 = 0.f;

    float4 P = s_c4[0];
    #pragma unroll 1
    for (int p = 0; p < nkept; ++p) {
        const float4 Pn = s_c4[p + 1];   // prefetch; sentinel slot makes it safe
        const float mm = P.x, vaL = P.y, vaR = P.z, vrc = P.w;
        const float msub = mm - 512.0f;                              // exact
        const float nden = (mm == 511.0f) ? -1.0f : (mm - 511.0f);   // -den, exact

#define EVAL(LF, ACC)                                                       \
        {                                                                   \
            const float q    = (LF) - mm;                                   \
            const float num  = q * msub;            /* exact int product */ \
            const float rq   = div_exact(num, nden, vrc); /* RN(num/den) */ \
            const float left = (q + 1.0f) + vaL;                            \
            const float rt   = (-1.0f + rq) + vaR;                          \
            const float base = ((LF) < mm) ? left : rt;                     \
            (ACC) += div_exact(base, -3.0f, C3) + 1.0f;                     \
        }

        EVAL(lf0, acc0)
        EVAL(lf1, acc1)
#undef EVAL
        P = Pn;
    }

    float2 res;
    res.x = (acc0 > 0.0f) ? 1.0f : 0.0f;
    res.y = (acc1 > 0.0f) ? 1.0f : 0.0f;
    *reinterpret_cast<float2*>(out + (size_t)b * SEQ_LEN + 2 * t) = res;
}

extern "C" void kernel_launch(void* const* d_in, const int* in_sizes, int n_in,
                              void* d_out, int out_size, void* d_ws, size_t ws_size,
                              hipStream_t stream)
{
    const float* tok   = (const float*)d_in[0];
    const float* sigma = (const float*)d_in[1];
    const float* pi    = (const float*)d_in[2];
    float* out = (float*)d_out;

    const int B = in_sizes[0] / NPROTO;   // 8192
    // Launch the SAME kernel twice (idempotent): forks launch-overhead floor
    // (dur ~22us) vs per-dispatch fixed cost (dur ~44us).
    adaptive_mask_kernel<<<B, TPB, 0, stream>>>(tok, sigma, pi, out);
    adaptive_mask_kernel<<<B, TPB, 0, stream>>>(tok, sigma, pi, out);
}

// Round 10
// 23.574 us; speedup vs baseline: 1.6880x; 1.6880x over previous
//
#include <hip/hip_runtime.h>

#define NPROTO 20
#define SEQ_LEN 512
#define TPB 64     // ONE wave per block & per row: barriers are intra-wave (cheap),
                   // no wave ever idles waiting for another wave's setup.

// Correctly-rounded a/3 via Markstein refinement (C3 = RN(1/3)):
// q0=RN(a*C3); r=fma(-3,q0,a) exact; q1=RN(q0+r*C3) == RN(a/3) for ALL f32 a
// (a/3 is exact or non-terminating -> never a rounding tie; proven bit-exact
// vs the harness in R3/R4/R6/R7/R9, absmax=0).
__device__ __forceinline__ float div3_exact(float a)
{
    const float C3 = 1.0f / 3.0f;
    const float q0 = a * C3;
    const float r  = fmaf(-3.0f, q0, a);
    return fmaf(r, C3, q0);
}

// Per (row,proto) params: {m, aL, aR, rc=RN(1/den)}. The in-loop right-side
// divide num/den uses the same Markstein form with rc (proven family:
// den integer in [1,510], num exact integer product < 2^18).
//
// Sentinel {m=0, aL=0, aR=-2, rc=0} yields val == 0.0f EXACTLY for every l:
//   rq: q0=num*0=+-0, r=fma(nden,+-0,num)=num, rq=fma(num,0,+-0)=+-0
//   rt = (-1.0 + +-0) + (-2) = -3; lf<0 never -> base=-3; val=RN(-3/3)+1=0.
// acc += 0.0f cannot change the (acc>0) sign test (only -0 -> +0, both fail >0).
__global__ __launch_bounds__(TPB)
void adaptive_mask_kernel(const float* __restrict__ tok,
                          const float* __restrict__ sigma,
                          const float* __restrict__ pi,
                          float* __restrict__ out)
{
    const int b    = blockIdx.x;
    const int lane = threadIdx.x;          // single wave: threadIdx == lane

    __shared__ __align__(16) float s_pi[NPROTO];
    __shared__ float4 s_c4[NPROTO + 3];    // compacted params + 3 sentinels

    float m = 0.f, aL = 0.f, aR = 0.f, rc = 0.f, piv = 0.f;
    if (lane < NPROTO) {
        const int idx = b * NPROTO + lane;
        const float tk = tok[idx];
        const float sg = sigma[idx];
        m  = rintf(fminf(fmaxf(tk, 1.0f), 511.0f));   // round-half-even
        aL = (0.001f * sg) * m;                       // CVL*sigma*m
        aR = (0.001f * sg) * (512.0f - m);            // CVR*sigma*(512-m)
        const float den = (m == 511.0f) ? 1.0f : (511.0f - m);
        rc  = 1.0f / den;                             // IEEE RN(1/den)
        piv = pi[idx];
        s_pi[lane] = piv;
    }
    __syncthreads();   // write -> barrier -> read (proven-safe pattern)

    // Every lane redundantly computes the sequential mean (bit-exact XLA order).
    float s = 0.0f;
    #pragma unroll
    for (int k = 0; k < 5; ++k) {
        const float4 v = *reinterpret_cast<const float4*>(&s_pi[4 * k]);
        s = (((s + v.x) + v.y) + v.z) + v.w;          // strict sequential order
    }
    const float mean = s / 20.0f;                     // IEEE divide

    const bool keep = (lane < NPROTO) && (piv >= mean);
    const unsigned long long bal = __ballot(keep);
    const int nk = __builtin_amdgcn_readfirstlane((int)__popcll(bal));
    if (keep) {       // compact kept params, ascending p (order == reference)
        const int dst = (int)__popcll(bal & ((1ull << lane) - 1ull));
        s_c4[dst] = make_float4(m, aL, aR, rc);
    }
    // zero-contribution sentinels (lanes 60..62 are never 'keep')
    if (lane == 60) s_c4[nk]     = make_float4(0.f, 0.f, -2.f, 0.f);
    if (lane == 61) s_c4[nk + 1] = make_float4(0.f, 0.f, -2.f, 0.f);
    if (lane == 62) s_c4[nk + 2] = make_float4(0.f, 0.f, -2.f, 0.f);
    __syncthreads();

    // Lane owns l = lane*8 .. lane*8+7.
    const float lb = (float)(lane * 8);
    float lf[8], acc[8];
    #pragma unroll
    for (int j = 0; j < 8; ++j) { lf[j] = lb + (float)j; acc[j] = 0.0f; }

    // Dense loop over kept protos, unroll-by-2 with register prefetch.
    // Reads reach at most s_c4[nk+2] (covered by sentinels).
    const int trips = __builtin_amdgcn_readfirstlane((nk + 1) >> 1);
    float4 P0 = s_c4[0];
    float4 P1 = s_c4[1];

    #pragma unroll 1
    for (int i = 0; i < trips; ++i) {
        const float4 N0 = s_c4[2 * i + 2];   // prefetch next pair
        const float4 N1 = s_c4[2 * i + 3];

#define PROTO(P)                                                             \
        {                                                                    \
            const float mm = (P).x, vaL = (P).y, vaR = (P).z, vrc = (P).w;   \
            const float m1   = mm - 1.0f;          /* exact */               \
            const float ms   = mm - 512.0f;        /* exact */               \
            const float mt   = mm * ms;            /* exact int, <2^18 */    \
            const float nden = (mm == 511.0f) ? -1.0f : (mm - 511.0f);       \
            _Pragma("unroll")                                                \
            for (int j = 0; j < 8; ++j) {                                    \
                const float e1   = lf[j] - m1;     /* == (q+1), exact */     \
                const float num  = fmaf(lf[j], ms, -mt); /* ==q*ms exact */  \
                const float q0   = num * vrc;                                \
                const float r    = fmaf(nden, q0, num);                      \
                const float rq   = fmaf(r, vrc, q0);     /* RN(num/den) */   \
                const float left = e1 + vaL;                                 \
                const float rt   = (-1.0f + rq) + vaR;                       \
                const float base = (lf[j] < mm) ? left : rt;                 \
                acc[j] += div3_exact(base) + 1.0f;                           \
            }                                                                \
        }

        PROTO(P0)
        PROTO(P1)
#undef PROTO
        P0 = N0;
        P1 = N1;
    }

    float4 r0, r1;
    r0.x = (acc[0] > 0.0f) ? 1.0f : 0.0f;
    r0.y = (acc[1] > 0.0f) ? 1.0f : 0.0f;
    r0.z = (acc[2] > 0.0f) ? 1.0f : 0.0f;
    r0.w = (acc[3] > 0.0f) ? 1.0f : 0.0f;
    r1.x = (acc[4] > 0.0f) ? 1.0f : 0.0f;
    r1.y = (acc[5] > 0.0f) ? 1.0f : 0.0f;
    r1.z = (acc[6] > 0.0f) ? 1.0f : 0.0f;
    r1.w = (acc[7] > 0.0f) ? 1.0f : 0.0f;

    float4* o = reinterpret_cast<float4*>(out + (size_t)b * SEQ_LEN + lane * 8);
    o[0] = r0;
    o[1] = r1;
}

extern "C" void kernel_launch(void* const* d_in, const int* in_sizes, int n_in,
                              void* d_out, int out_size, void* d_ws, size_t ws_size,
                              hipStream_t stream)
{
    const float* tok   = (const float*)d_in[0];
    const float* sigma = (const float*)d_in[1];
    const float* pi    = (const float*)d_in[2];
    float* out = (float*)d_out;

    const int B = in_sizes[0] / NPROTO;   // 8192 rows, one wave each
    adaptive_mask_kernel<<<B, TPB, 0, stream>>>(tok, sigma, pi, out);
}

// Round 11
// 23.428 us; speedup vs baseline: 1.6985x; 1.0062x over previous
//
#include <hip/hip_runtime.h>

#define NPROTO 20
#define SEQ_LEN 512
#define RPB 4                  // rows per block == waves per block
#define TPB (RPB * 64)         // 256 threads; wave w owns row RPB*b + w

// Correctly-rounded a/3 via Markstein refinement (C3 = RN(1/3)):
// q0=RN(a*C3); r=fma(-3,q0,a) exact; q1=RN(q0+r*C3) == RN(a/3) for ALL f32 a.
// Proven bit-exact vs the harness in R3/R4/R6/R7/R9/R10 (absmax=0).
__device__ __forceinline__ float div3_exact(float a)
{
    const float C3 = 1.0f / 3.0f;
    const float q0 = a * C3;
    const float r  = fmaf(-3.0f, q0, a);
    return fmaf(r, C3, q0);
}

// Sentinel {m=0, aL=0, aR=-2, rc=0} yields val == 0.0f EXACTLY for every l
// (proven on-device in R10): rq collapses to +-0, rt = (-1 +- 0) - 2 = -3,
// lf<0 never -> base=-3, val = RN(-3/3)+1 = 0; acc += 0 can't change acc>0.
__global__ __launch_bounds__(TPB)
void adaptive_mask_kernel(const float* __restrict__ tok,
                          const float* __restrict__ sigma,
                          const float* __restrict__ pi,
                          float* __restrict__ out)
{
    const int lane = threadIdx.x & 63;
    const int wid  = __builtin_amdgcn_readfirstlane((int)(threadIdx.x >> 6));
    const int row  = blockIdx.x * RPB + wid;

    // per-wave slabs: no inter-wave data flow at all (barriers are only for
    // the compiler-visible write->read ordering; waves are symmetric, so the
    // coupling costs ~nothing)
    __shared__ __align__(16) float s_pi[RPB][NPROTO];        // 80 B/wave, 16-aligned
    __shared__ float4 s_c4[RPB][NPROTO + 3];                 // params + 3 sentinels

    float m = 0.f, aL = 0.f, aR = 0.f, rc = 0.f, piv = 0.f;
    if (lane < NPROTO) {
        const int idx = row * NPROTO + lane;
        const float tk = tok[idx];
        const float sg = sigma[idx];
        m  = rintf(fminf(fmaxf(tk, 1.0f), 511.0f));   // round-half-even
        aL = (0.001f * sg) * m;                       // CVL*sigma*m
        aR = (0.001f * sg) * (512.0f - m);            // CVR*sigma*(512-m)
        const float den = (m == 511.0f) ? 1.0f : (511.0f - m);
        rc  = 1.0f / den;                             // IEEE RN(1/den)
        piv = pi[idx];
        s_pi[wid][lane] = piv;
    }
    __syncthreads();   // write -> barrier -> read (proven-safe pattern)

    // Every lane redundantly computes its row's sequential mean (XLA order).
    float s = 0.0f;
    #pragma unroll
    for (int k = 0; k < 5; ++k) {
        const float4 v = *reinterpret_cast<const float4*>(&s_pi[wid][4 * k]);
        s = (((s + v.x) + v.y) + v.z) + v.w;          // strict sequential order
    }
    const float mean = s / 20.0f;                     // IEEE divide

    const bool keep = (lane < NPROTO) && (piv >= mean);
    const unsigned long long bal = __ballot(keep);
    const int nk = __builtin_amdgcn_readfirstlane((int)__popcll(bal));
    if (keep) {       // compact kept params, ascending p (order == reference)
        const int dst = (int)__popcll(bal & ((1ull << lane) - 1ull));
        s_c4[wid][dst] = make_float4(m, aL, aR, rc);
    }
    // zero-contribution sentinels (lanes 60..62 are never 'keep')
    if (lane == 60) s_c4[wid][nk]     = make_float4(0.f, 0.f, -2.f, 0.f);
    if (lane == 61) s_c4[wid][nk + 1] = make_float4(0.f, 0.f, -2.f, 0.f);
    if (lane == 62) s_c4[wid][nk + 2] = make_float4(0.f, 0.f, -2.f, 0.f);
    __syncthreads();

    // Lane owns l = 4*lane + j (j=0..3) and l = 256 + 4*lane + j (j=4..7):
    // both float4 stores are fully coalesced (1 KB contiguous per wave).
    const float lbA = (float)(4 * lane);          // exact
    const float lbB = lbA + 256.0f;               // exact
    float lf[8], acc[8];
    #pragma unroll
    for (int j = 0; j < 4; ++j) { lf[j] = lbA + (float)j; acc[j] = 0.0f; }
    #pragma unroll
    for (int j = 4; j < 8; ++j) { lf[j] = lbB + (float)(j - 4); acc[j] = 0.0f; }

    // Dense loop over kept protos, unroll-by-2 with register prefetch.
    // Max read index = 2*trips+1 <= nk+2 (covered by the 3 sentinels).
    const int trips = __builtin_amdgcn_readfirstlane((nk + 1) >> 1);
    float4 P0 = s_c4[wid][0];
    float4 P1 = s_c4[wid][1];

    #pragma unroll 1
    for (int i = 0; i < trips; ++i) {
        const float4 N0 = s_c4[wid][2 * i + 2];   // prefetch next pair
        const float4 N1 = s_c4[wid][2 * i + 3];

#define PROTO(P)                                                             \
        {                                                                    \
            const float mm = (P).x, vaL = (P).y, vaR = (P).z, vrc = (P).w;   \
            const float m1   = mm - 1.0f;          /* exact */               \
            const float ms   = mm - 512.0f;        /* exact */               \
            const float mt   = mm * ms;            /* exact int, <2^18 */    \
            const float nden = (mm == 511.0f) ? -1.0f : (mm - 511.0f);       \
            _Pragma("unroll")                                                \
            for (int j = 0; j < 8; ++j) {                                    \
                const float e1   = lf[j] - m1;     /* == (q+1), exact */     \
                const float num  = fmaf(lf[j], ms, -mt); /* ==q*ms exact */  \
                const float q0   = num * vrc;                                \
                const float r    = fmaf(nden, q0, num);                      \
                const float rq   = fmaf(r, vrc, q0);     /* RN(num/den) */   \
                const float left = e1 + vaL;                                 \
                const float rt   = (-1.0f + rq) + vaR;                       \
                const float base = (lf[j] < mm) ? left : rt;                 \
                acc[j] += div3_exact(base) + 1.0f;                           \
            }                                                                \
        }

        PROTO(P0)
        PROTO(P1)
#undef PROTO
        P0 = N0;
        P1 = N1;
    }

    float4 r0, r1;
    r0.x = (acc[0] > 0.0f) ? 1.0f : 0.0f;
    r0.y = (acc[1] > 0.0f) ? 1.0f : 0.0f;
    r0.z = (acc[2] > 0.0f) ? 1.0f : 0.0f;
    r0.w = (acc[3] > 0.0f) ? 1.0f : 0.0f;
    r1.x = (acc[4] > 0.0f) ? 1.0f : 0.0f;
    r1.y = (acc[5] > 0.0f) ? 1.0f : 0.0f;
    r1.z = (acc[6] > 0.0f) ? 1.0f : 0.0f;
    r1.w = (acc[7] > 0.0f) ? 1.0f : 0.0f;

    float* orow = out + (size_t)row * SEQ_LEN;
    *reinterpret_cast<float4*>(orow + 4 * lane)       = r0;
    *reinterpret_cast<float4*>(orow + 256 + 4 * lane) = r1;
}

extern "C" void kernel_launch(void* const* d_in, const int* in_sizes, int n_in,
                              void* d_out, int out_size, void* d_ws, size_t ws_size,
                              hipStream_t stream)
{
    const float* tok   = (const float*)d_in[0];
    const float* sigma = (const float*)d_in[1];
    const float* pi    = (const float*)d_in[2];
    float* out = (float*)d_out;

    const int B = in_sizes[0] / NPROTO;   // 8192 rows
    adaptive_mask_kernel<<<B / RPB, TPB, 0, stream>>>(tok, sigma, pi, out);
}